// Round 4
// baseline (2990.206 us; speedup 1.0000x reference)
//
#include <hip/hip_runtime.h>
#include <math.h>

typedef __attribute__((ext_vector_type(8))) short bf16x8;
typedef __attribute__((ext_vector_type(4))) float f32x4;

#define BB 64
#define TT 2048
#define RR 256
#define BLK 24
#define NTHR 256
#define HB_PAD 776   // 768 + 8: rows 16B-aligned; far-read conflicts modest (4-way)
#define HW_PAD 288   // var stride 144 dw = 16 mod 32: hi/lo halves hit disjoint
                     // 16-bank halves; each 4-bank group is pure broadcast -> 0 conflicts

#define MFMA(a, b, c) __builtin_amdgcn_mfma_f32_16x16x32_bf16((a), (b), (c), 0, 0, 0)

__device__ __forceinline__ unsigned short f2bf(float f) {
    unsigned u = __float_as_uint(f);
    return (unsigned short)((u + 0x7FFFu + ((u >> 16) & 1u)) >> 16);  // RNE
}
__device__ __forceinline__ float bf2f(unsigned short h) {
    return __uint_as_float(((unsigned)h) << 16);
}
// Branch-free tanh: 1 - 2/(1+e^{2x}).
__device__ __forceinline__ float fast_tanh(float x) {
    float e = __expf(2.0f * x);
    return 1.0f - 2.0f * __builtin_amdgcn_rcpf(1.0f + e);
}

// ---- Pre-pass: pack tw[tap]*W_fb[tap] into MFMA B-fragment order (bf16) ----
// Layout: chunk c = (tap*8 + kt)*16 + nt; element = c*512 + lane*8 (ushorts).
// Fragment: lane l holds B[k = 32*kt + 8*(l>>4) + j][n = 16*nt + (l&15)], j=0..7.
__global__ void pack_weights(const float* __restrict__ W_fb,
                             const float* __restrict__ tapw,
                             unsigned short* __restrict__ bp) {
    int gid = blockIdx.x * 256 + threadIdx.x;      // 40960 threads
    int l = gid & 63, c = gid >> 6;                // c: 0..639
    int tap = c >> 7;
    int rem = c & 127;
    int kt = rem >> 4, nt = rem & 15;

    float v0 = tapw[0], v1 = tapw[1], v2 = tapw[2], v3 = tapw[3], v4 = tapw[4];
    float mx = fmaxf(fmaxf(fmaxf(v0, v1), fmaxf(v2, v3)), v4);
    float e0 = expf(v0 - mx), e1 = expf(v1 - mx), e2 = expf(v2 - mx),
          e3 = expf(v3 - mx), e4 = expf(v4 - mx);
    float inv = 1.0f / (e0 + e1 + e2 + e3 + e4);
    float tws[5] = {e0 * inv, e1 * inv, e2 * inv, e3 * inv, e4 * inv};
    float tw = tws[tap];

    int kbase = 32 * kt + 8 * (l >> 4);
    int n = 16 * nt + (l & 15);
    const float* W = W_fb + tap * 65536;
    unsigned short t[8];
#pragma unroll
    for (int j = 0; j < 8; ++j) t[j] = f2bf(tw * W[(kbase + j) * 256 + n]);
    uint4 o;
    o.x = (unsigned)t[0] | ((unsigned)t[1] << 16);
    o.y = (unsigned)t[2] | ((unsigned)t[3] << 16);
    o.z = (unsigned)t[4] | ((unsigned)t[5] << 16);
    o.w = (unsigned)t[6] | ((unsigned)t[7] << 16);
    *(uint4*)(bp + (size_t)(c * 64 + l) * 8) = o;
}

// ---- Main kernel: one WG per batch, 4 waves; wave w owns s in [64w, 64w+64) ----
// R4 changes vs 2128us R3:
//  (1) 4 waves x 4 col-tiles (was 8 x 2). A-fragment LDS reads are per-wave
//      regardless of column count -> tap1 64->32, tap4 16->8 instr/step/CU,
//      far A-reads 576->288/block. MFMA count per CU unchanged (32/SIMD/step).
//      All waves identical work (no R2-style role divergence / extra barriers).
//  (2) HW_PAD 264->288: hi/lo row-packed reads now conflict-free (var offset
//      lands on bank+16; disjoint bank halves, broadcast within groups).
//  (3) B-residents 64 frags = 256 VGPR (1 wave/SIMD -> 512 VGPR budget).
__global__ __launch_bounds__(NTHR, 1)
void reservoir_mfma(const float* __restrict__ x,
                    const float* __restrict__ W_in,
                    const float* __restrict__ bias,
                    const unsigned short* __restrict__ bp,
                    float* __restrict__ out)
{
    const int b    = blockIdx.x;
    const int tid  = threadIdx.x;
    const int lane = tid & 63;
    const int w    = tid >> 6;          // 0..3
    const int l15  = lane & 15;
    const int quad = lane >> 4;

    __shared__ float xs[TT];                             // 8 KB
    __shared__ unsigned short hwinb[8][2][HW_PAD];       // 9 KB: h ring, bf16 hi/lo
    __shared__ unsigned short hbcb[BLK][2][HB_PAD];      // 72.8 KB: far history hi/lo
    __shared__ float Gl[BLK][257];                       // 24.1 KB: far + drive + bias
    __shared__ float hob[BLK][RR];                       // 24 KB: block h output buffer

    for (int i = tid; i < TT; i += NTHR) xs[i] = x[b * TT + i];
    {
        unsigned* hz = (unsigned*)&hwinb[0][0][0];
        for (int i = tid; i < 8 * 2 * HW_PAD / 2; i += NTHR) hz[i] = 0u;
    }

    // Resident B-fragments: tap d=1 (b1) and d=4 (b4), 4 col-tiles each. 256 VGPR.
    const bf16x8* bpv = (const bf16x8*)bp;
    bf16x8 b1[8][4], b4[8][4];
#pragma unroll
    for (int kt = 0; kt < 8; ++kt)
#pragma unroll
        for (int u = 0; u < 4; ++u) {
            int nt = 4 * w + u;
            b1[kt][u] = bpv[((0 * 8 + kt) * 16 + nt) * 64 + lane];
            b4[kt][u] = bpv[((1 * 8 + kt) * 16 + nt) * 64 + lane];
        }

    float win[4], bi[4], hp[4];
#pragma unroll
    for (int nt = 0; nt < 4; ++nt) {
        int s = 64 * w + 16 * nt + l15;
        win[nt] = W_in[s];
        bi[nt]  = bias[s];
        hp[nt]  = 0.0f;
    }

    const float* outr = out + (size_t)b * TT * RR;
    float*       outw = out + (size_t)b * TT * RR;

    // Row-packed A-operand base pointers (var folded into the lane index):
    const unsigned short* hw1v = &hwinb[0][l15 & 1][0];         // tap1: row parity
    const unsigned short* hw4v = &hwinb[0][(l15 >> 2) & 1][0];  // tap4: rows 0-3/4-7
    const unsigned short* fa1  = &hbcb[16 + (l15 & 7)][(l15 >> 3) & 1][0];  // far t1
    const size_t HWSLOT = 2 * HW_PAD;   // ushorts per hwinb slot

    __syncthreads();

    for (int t0 = 0; t0 < TT; t0 += BLK) {
        // ---- stage far history (taps 24/96/168) into hbcb, bf16 hi/lo ----
        // tap-24 rows come from previous block's hob (still resident in LDS).
#pragma unroll
        for (int it = 0; it < 18; ++it) {                 // 18*256 = 4608 = 24*768/4
            int i = it * NTHR + tid;
            int j = i / 192;
            int p = i - j * 192;
            int r = 4 * p;
            int kf = r >> 8, rr = r & 255;
            float4 v = {0.f, 0.f, 0.f, 0.f};
            if (kf == 0) {
                if (t0 > 0) v = *(const float4*)&hob[j][rr];
            } else {
                int dk = (kf == 1) ? 96 : 168;
                int tt = t0 + j - dk;
                if (tt >= 0) v = *(const float4*)(outr + (size_t)tt * RR + rr);
            }
            unsigned short h0 = f2bf(v.x), h1 = f2bf(v.y), h2 = f2bf(v.z), h3 = f2bf(v.w);
            unsigned short q0 = f2bf(v.x - bf2f(h0)), q1 = f2bf(v.y - bf2f(h1)),
                           q2 = f2bf(v.z - bf2f(h2)), q3 = f2bf(v.w - bf2f(h3));
            uint2 H = { (unsigned)h0 | ((unsigned)h1 << 16), (unsigned)h2 | ((unsigned)h3 << 16) };
            uint2 Q = { (unsigned)q0 | ((unsigned)q1 << 16), (unsigned)q2 | ((unsigned)q3 << 16) };
            *(uint2*)&hbcb[j][0][r] = H;
            *(uint2*)&hbcb[j][1][r] = Q;
        }
        __syncthreads();

        // ---- far GEMM: C[24 j][64 s/wave] over K=768; tile0 hi+lo chains,
        //      tile1 row-packed; B-fragment prefetch depth 1 ----
        f32x4 zf = {0.f, 0.f, 0.f, 0.f};
        f32x4 cf0a[4], cf0b[4], cf1[4];
#pragma unroll
        for (int nt = 0; nt < 4; ++nt) { cf0a[nt] = zf; cf0b[nt] = zf; cf1[nt] = zf; }
        const int r0a = l15;              // m-tile 0: j = 0..15
        bf16x8 nB[4];
#pragma unroll
        for (int nt = 0; nt < 4; ++nt)
            nB[nt] = bpv[((16 + 0) * 16 + 4 * w + nt) * 64 + lane];
#pragma unroll 1
        for (int ft = 0; ft < 24; ++ft) {
            bf16x8 B[4];
#pragma unroll
            for (int nt = 0; nt < 4; ++nt) B[nt] = nB[nt];
            int nf = (ft < 23) ? ft + 1 : 23;             // prefetch next (dup at end)
#pragma unroll
            for (int nt = 0; nt < 4; ++nt)
                nB[nt] = bpv[((16 + nf) * 16 + 4 * w + nt) * 64 + lane];
            int ro = 32 * ft + 8 * quad;
            bf16x8 a00 = *(const bf16x8*)&hbcb[r0a][0][ro];
            bf16x8 a01 = *(const bf16x8*)&hbcb[r0a][1][ro];
            bf16x8 a1  = *(const bf16x8*)&fa1[ro];
#pragma unroll
            for (int nt = 0; nt < 4; ++nt) {
                cf0a[nt] = MFMA(a00, B[nt], cf0a[nt]);
                cf0b[nt] = MFMA(a01, B[nt], cf0b[nt]);
                cf1[nt]  = MFMA(a1,  B[nt], cf1[nt]);
            }
        }
        // tile1 full = hi (quads 0,1) + lo (quads 2,3): combine across lane^32
        float cf1f[4][4];
#pragma unroll
        for (int nt = 0; nt < 4; ++nt)
#pragma unroll
            for (int i = 0; i < 4; ++i)
                cf1f[nt][i] = cf1[nt][i] + __shfl_xor(cf1[nt][i], 32, 64);
        // writeback + fold bias and drive: Gl[j][s] = far[j][s] + bias[s] + x[t0+j]*Win[s]
#pragma unroll
        for (int i = 0; i < 4; ++i) {
            int j0 = 4 * quad + i;
            int tx0 = t0 + j0; float xv0 = xs[tx0 < TT ? tx0 : TT - 1];
#pragma unroll
            for (int nt = 0; nt < 4; ++nt) {
                int s = 64 * w + 16 * nt + l15;
                Gl[j0][s] = (cf0a[nt][i] + cf0b[nt][i]) + bi[nt] + xv0 * win[nt];
            }
            int j1 = 16 + 4 * quad + i;
            if (j1 < BLK) {
                int tx1 = t0 + j1; float xv1 = xs[tx1 < TT ? tx1 : TT - 1];
#pragma unroll
                for (int nt = 0; nt < 4; ++nt) {
                    int s = 64 * w + 16 * nt + l15;
                    Gl[j1][s] = cf1f[nt][i] + bi[nt] + xv1 * win[nt];
                }
            }
        }
        __syncthreads();

        // ---- sequential sub-blocks of 4 steps ----
        const int tend = (t0 + BLK < TT) ? (t0 + BLK) : TT;
#pragma unroll 1
        for (int t4 = t0; t4 < tend; t4 += 4) {
            // tap d=4, row-packed: rows 0-3 = h(t4-4+u) hi, rows 4-7 = lo.
            f32x4 c4[4];
#pragma unroll
            for (int nt = 0; nt < 4; ++nt) c4[nt] = zf;
            const int sl = (t4 - 4 + (l15 & 3)) & 7;
            const unsigned short* hw4 = hw4v + (size_t)sl * HWSLOT;
#pragma unroll
            for (int kt = 0; kt < 8; ++kt) {
                int ro = 32 * kt + 8 * quad;
                bf16x8 a = *(const bf16x8*)&hw4[ro];
#pragma unroll
                for (int nt = 0; nt < 4; ++nt) c4[nt] = MFMA(a, b4[kt][nt], c4[nt]);
            }
            // hi steps on quads 0,1 regs; lo on quads 2,3: combine across lane^16
            float c4f[4][4];
#pragma unroll
            for (int nt = 0; nt < 4; ++nt)
#pragma unroll
                for (int u2 = 0; u2 < 4; ++u2)
                    c4f[nt][u2] = c4[nt][u2] + __shfl_xor(c4[nt][u2], 16, 64);
            // 4 sequential steps; tap d=1 per step, row-packed hi/lo (1 chain/nt)
#pragma unroll
            for (int u = 0; u < 4; ++u) {
                const int t = t4 + u;
                const int sp = (t - 1) & 7;
                const unsigned short* hw1 = hw1v + (size_t)sp * HWSLOT;
                f32x4 c1[4];
#pragma unroll
                for (int nt = 0; nt < 4; ++nt) c1[nt] = zf;
#pragma unroll
                for (int kt = 0; kt < 8; ++kt) {
                    int ro = 32 * kt + 8 * quad;
                    bf16x8 a = *(const bf16x8*)&hw1[ro];
#pragma unroll
                    for (int nt = 0; nt < 4; ++nt) c1[nt] = MFMA(a, b1[kt][nt], c1[nt]);
                }
                // update (valid on lanes 0..15: rows 0,1 -> quad0 regs 0,1)
                const int jj = t - t0;
                const int wsl = t & 7;
                float hn[4];
#pragma unroll
                for (int nt = 0; nt < 4; ++nt) {
                    int s = 64 * w + 16 * nt + l15;
                    float f = (c1[nt][0] + c1[nt][1]) + c4f[nt][u] + Gl[jj][s];
                    hn[nt] = 0.9f * hp[nt] + 0.1f * fast_tanh(f);
                    hp[nt] = hn[nt];
                }
                if (lane < 16) {
#pragma unroll
                    for (int nt = 0; nt < 4; ++nt) {
                        int s = 64 * w + 16 * nt + l15;
                        unsigned short hh = f2bf(hn[nt]);
                        hwinb[wsl][0][s] = hh;
                        hwinb[wsl][1][s] = f2bf(hn[nt] - bf2f(hh));
                        hob[jj][s] = hn[nt];
                    }
                }
                __syncthreads();
            }
        }

        // ---- flush hob -> out, coalesced float4 (drains at next block's barrier;
        //      earliest global re-read of these rows is 3 blocks later) ----
        {
            const int nf4 = (tend - t0) * (RR / 4);       // 1536, or 512 in last block
            const float4* src = (const float4*)&hob[0][0];
            float4* dst = (float4*)(outw + (size_t)t0 * RR);
#pragma unroll
            for (int it = 0; it < 6; ++it) {
                int idx = it * NTHR + tid;
                if (idx < nf4) dst[idx] = src[idx];
            }
        }
    }
}

extern "C" void kernel_launch(void* const* d_in, const int* in_sizes, int n_in,
                              void* d_out, int out_size, void* d_ws, size_t ws_size,
                              hipStream_t stream) {
    const float* x    = (const float*)d_in[0];   // (64, 2048, 1)
    const float* W_in = (const float*)d_in[1];   // (256, 1)
    const float* W_fb = (const float*)d_in[2];   // (5, 256, 256)
    const float* tapw = (const float*)d_in[3];   // (5,)
    const float* bias = (const float*)d_in[4];   // (256,)
    float* out = (float*)d_out;                  // (64, 2048, 256)
    unsigned short* bp = (unsigned short*)d_ws;  // 640 KB packed bf16 B-fragments

    pack_weights<<<160, 256, 0, stream>>>(W_fb, tapw, bp);
    reservoir_mfma<<<BB, NTHR, 0, stream>>>(x, W_in, bias, bp, out);
}

// Round 8
// 1960.018 us; speedup vs baseline: 1.5256x; 1.5256x over previous
//
#include <hip/hip_runtime.h>
#include <math.h>

typedef __attribute__((ext_vector_type(8))) short bf16x8;
typedef __attribute__((ext_vector_type(4))) float f32x4;

#define BB 64
#define TT 2048
#define RR 256
#define BLK 24
#define NTHR 512
#define HB_PAD 776   // 768 + 8: rows 16B-aligned
#define HW_PAD 288   // var stride 144 dw = 16 mod 32: hi/lo rows hit disjoint
                     // 16-bank halves; conflict-free row-packed reads (R4-proven)

#define MFMA(a, b, c) __builtin_amdgcn_mfma_f32_16x16x32_bf16((a), (b), (c), 0, 0, 0)

__device__ __forceinline__ unsigned short f2bf(float f) {
    unsigned u = __float_as_uint(f);
    return (unsigned short)((u + 0x7FFFu + ((u >> 16) & 1u)) >> 16);  // RNE
}
__device__ __forceinline__ float bf2f(unsigned short h) {
    return __uint_as_float(((unsigned)h) << 16);
}
// Branch-free tanh: 1 - 2/(1+e^{2x}).
__device__ __forceinline__ float fast_tanh(float x) {
    float e = __expf(2.0f * x);
    return 1.0f - 2.0f * __builtin_amdgcn_rcpf(1.0f + e);
}

// ---- Pre-pass: pack tw[tap]*W_fb[tap] into MFMA B-fragment order (bf16) ----
// Layout: chunk c = (tap*8 + kt)*16 + nt; element = c*512 + lane*8 (ushorts).
// Fragment: lane l holds B[k = 32*kt + 8*(l>>4) + j][n = 16*nt + (l&15)], j=0..7.
__global__ void pack_weights(const float* __restrict__ W_fb,
                             const float* __restrict__ tapw,
                             unsigned short* __restrict__ bp) {
    int gid = blockIdx.x * 256 + threadIdx.x;      // 40960 threads
    int l = gid & 63, c = gid >> 6;                // c: 0..639
    int tap = c >> 7;
    int rem = c & 127;
    int kt = rem >> 4, nt = rem & 15;

    float v0 = tapw[0], v1 = tapw[1], v2 = tapw[2], v3 = tapw[3], v4 = tapw[4];
    float mx = fmaxf(fmaxf(fmaxf(v0, v1), fmaxf(v2, v3)), v4);
    float e0 = expf(v0 - mx), e1 = expf(v1 - mx), e2 = expf(v2 - mx),
          e3 = expf(v3 - mx), e4 = expf(v4 - mx);
    float inv = 1.0f / (e0 + e1 + e2 + e3 + e4);
    float tws[5] = {e0 * inv, e1 * inv, e2 * inv, e3 * inv, e4 * inv};
    float tw = tws[tap];

    int kbase = 32 * kt + 8 * (l >> 4);
    int n = 16 * nt + (l & 15);
    const float* W = W_fb + tap * 65536;
    unsigned short t[8];
#pragma unroll
    for (int j = 0; j < 8; ++j) t[j] = f2bf(tw * W[(kbase + j) * 256 + n]);
    uint4 o;
    o.x = (unsigned)t[0] | ((unsigned)t[1] << 16);
    o.y = (unsigned)t[2] | ((unsigned)t[3] << 16);
    o.z = (unsigned)t[4] | ((unsigned)t[5] << 16);
    o.w = (unsigned)t[6] | ((unsigned)t[7] << 16);
    *(uint4*)(bp + (size_t)(c * 64 + l) * 8) = o;
}

// ---- Main kernel: one WG per batch, 8 waves; wave w owns s in [32w, 32w+32) ----
// R6 = R5 with the Gl2 index bug fixed (16*w + l15, was 32*w + l15 -> row
// overflow corrupted neighboring rows). R5 changes vs 2128us R3:
//  (1) HW_PAD 264->288: row-packed tap1/tap4 reads conflict-free (R4-validated).
//  (2) Packed h-write: all quads compute identical h (row-parity fills ALL A-rows,
//      so C rows 4q,4q+1 valid on every quad; hi+lo commutative -> bitwise equal).
//      One ds_write_b16 (quad selects {hi,lo}x{s0,s1}) + one guarded b32 hob
//      write: 6 LDS write instr -> 2.
//  (3) Gl as float2: 1 b64 read/step/wave instead of 2 b32.
//  (4) Far-GEMM B-fragment prefetch depth 3 (rotation), hides L2 latency.
__global__ __launch_bounds__(NTHR, 1)
void reservoir_mfma(const float* __restrict__ x,
                    const float* __restrict__ W_in,
                    const float* __restrict__ bias,
                    const unsigned short* __restrict__ bp,
                    float* __restrict__ out)
{
    const int b    = blockIdx.x;
    const int tid  = threadIdx.x;
    const int lane = tid & 63;
    const int w    = tid >> 6;
    const int l15  = lane & 15;
    const int quad = lane >> 4;

    __shared__ float xs[TT];                             // 8 KB
    __shared__ unsigned short hwinb[8][2][HW_PAD];       // 9 KB: h ring, bf16 hi/lo
    __shared__ unsigned short hbcb[BLK][2][HB_PAD];      // 72.8 KB: far history hi/lo
    __shared__ float2 Gl2[BLK][130];                     // 25 KB: far + drive + bias
    __shared__ float hob[BLK][RR];                       // 24 KB: block h output buffer

    for (int i = tid; i < TT; i += NTHR) xs[i] = x[b * TT + i];
    {
        unsigned* hz = (unsigned*)&hwinb[0][0][0];
        for (int i = tid; i < 8 * 2 * HW_PAD / 2; i += NTHR) hz[i] = 0u;
    }

    // Resident B-fragments: tap d=1 (b1) and d=4 (b4). 128 VGPRs total.
    const bf16x8* bpv = (const bf16x8*)bp;
    bf16x8 b1[8][2], b4[8][2];
#pragma unroll
    for (int kt = 0; kt < 8; ++kt)
#pragma unroll
        for (int u = 0; u < 2; ++u) {
            int nt = 2 * w + u;
            b1[kt][u] = bpv[((0 * 8 + kt) * 16 + nt) * 64 + lane];
            b4[kt][u] = bpv[((1 * 8 + kt) * 16 + nt) * 64 + lane];
        }

    const int s0g = 32 * w + l15, s1g = s0g + 16;
    const float win0 = W_in[s0g], win1 = W_in[s1g];
    const float bi0 = bias[s0g], bi1 = bias[s1g];
    float hp0 = 0.0f, hp1 = 0.0f;

    const float* outr = out + (size_t)b * TT * RR;
    float*       outw = out + (size_t)b * TT * RR;

    // Row-packed A-operand base pointers (var folded into the lane index):
    const unsigned short* hw1v = &hwinb[0][l15 & 1][0];         // tap1: row parity
    const unsigned short* hw4v = &hwinb[0][(l15 >> 2) & 1][0];  // tap4: rows 0-3/4-7
    const unsigned short* fa1  = &hbcb[16 + (l15 & 7)][(l15 >> 3) & 1][0];  // far t1
    const size_t HWSLOT = 2 * HW_PAD;   // ushorts per hwinb slot

    // Packed-write lane mapping: quad -> {hi,lo} x {s0,s1}
    const int varw  = quad >> 1;                     // 0: hi, 1: lo
    const int s_w   = 32 * w + l15 + ((quad & 1) << 4);
    unsigned short* const hwb = &hwinb[0][0][0];
    const unsigned hw_off = (unsigned)(varw * HW_PAD + s_w);

    __syncthreads();

    for (int t0 = 0; t0 < TT; t0 += BLK) {
        // ---- stage far history (taps 24/96/168) into hbcb, bf16 hi/lo ----
        // tap-24 rows come from previous block's hob (still resident in LDS).
#pragma unroll
        for (int it = 0; it < 9; ++it) {                  // 9*512 = 4608 = 24*768/4
            int i = it * NTHR + tid;
            int j = i / 192;
            int p = i - j * 192;
            int r = 4 * p;
            int kf = r >> 8, rr = r & 255;
            float4 v = {0.f, 0.f, 0.f, 0.f};
            if (kf == 0) {
                if (t0 > 0) v = *(const float4*)&hob[j][rr];
            } else {
                int dk = (kf == 1) ? 96 : 168;
                int tt = t0 + j - dk;
                if (tt >= 0) v = *(const float4*)(outr + (size_t)tt * RR + rr);
            }
            unsigned short h0 = f2bf(v.x), h1 = f2bf(v.y), h2 = f2bf(v.z), h3 = f2bf(v.w);
            unsigned short q0 = f2bf(v.x - bf2f(h0)), q1 = f2bf(v.y - bf2f(h1)),
                           q2 = f2bf(v.z - bf2f(h2)), q3 = f2bf(v.w - bf2f(h3));
            uint2 H = { (unsigned)h0 | ((unsigned)h1 << 16), (unsigned)h2 | ((unsigned)h3 << 16) };
            uint2 Q = { (unsigned)q0 | ((unsigned)q1 << 16), (unsigned)q2 | ((unsigned)q3 << 16) };
            *(uint2*)&hbcb[j][0][r] = H;
            *(uint2*)&hbcb[j][1][r] = Q;
        }
        __syncthreads();

        // ---- far GEMM: C[24 j][32 s/wave] over K=768; tile0 hi+lo chains,
        //      tile1 row-packed; B prefetch depth 3 (rotation) ----
        f32x4 zf = {0.f, 0.f, 0.f, 0.f};
        f32x4 cf00a = zf, cf01a = zf, cf00b = zf, cf01b = zf, cf10 = zf, cf11 = zf;
        const int r0a = l15;              // m-tile 0: j = 0..15
        const int cw0 = 2 * w, cw1 = 2 * w + 1;
        bf16x8 p0A = bpv[((16 + 0) * 16 + cw0) * 64 + lane];
        bf16x8 p0B = bpv[((16 + 0) * 16 + cw1) * 64 + lane];
        bf16x8 p1A = bpv[((16 + 1) * 16 + cw0) * 64 + lane];
        bf16x8 p1B = bpv[((16 + 1) * 16 + cw1) * 64 + lane];
        bf16x8 p2A = bpv[((16 + 2) * 16 + cw0) * 64 + lane];
        bf16x8 p2B = bpv[((16 + 2) * 16 + cw1) * 64 + lane];
#pragma unroll 1
        for (int g = 0; g < 8; ++g) {
            const int base = 3 * g;
            {
                int ro = 32 * base + 8 * quad;
                bf16x8 a00 = *(const bf16x8*)&hbcb[r0a][0][ro];
                bf16x8 a01 = *(const bf16x8*)&hbcb[r0a][1][ro];
                bf16x8 a1  = *(const bf16x8*)&fa1[ro];
                cf00a = MFMA(a00, p0A, cf00a); cf01a = MFMA(a00, p0B, cf01a);
                cf00b = MFMA(a01, p0A, cf00b); cf01b = MFMA(a01, p0B, cf01b);
                cf10  = MFMA(a1,  p0A, cf10);  cf11  = MFMA(a1,  p0B, cf11);
                int nf = base + 3; if (nf > 23) nf = 23;
                p0A = bpv[((16 + nf) * 16 + cw0) * 64 + lane];
                p0B = bpv[((16 + nf) * 16 + cw1) * 64 + lane];
            }
            {
                int ro = 32 * (base + 1) + 8 * quad;
                bf16x8 a00 = *(const bf16x8*)&hbcb[r0a][0][ro];
                bf16x8 a01 = *(const bf16x8*)&hbcb[r0a][1][ro];
                bf16x8 a1  = *(const bf16x8*)&fa1[ro];
                cf00a = MFMA(a00, p1A, cf00a); cf01a = MFMA(a00, p1B, cf01a);
                cf00b = MFMA(a01, p1A, cf00b); cf01b = MFMA(a01, p1B, cf01b);
                cf10  = MFMA(a1,  p1A, cf10);  cf11  = MFMA(a1,  p1B, cf11);
                int nf = base + 4; if (nf > 23) nf = 23;
                p1A = bpv[((16 + nf) * 16 + cw0) * 64 + lane];
                p1B = bpv[((16 + nf) * 16 + cw1) * 64 + lane];
            }
            {
                int ro = 32 * (base + 2) + 8 * quad;
                bf16x8 a00 = *(const bf16x8*)&hbcb[r0a][0][ro];
                bf16x8 a01 = *(const bf16x8*)&hbcb[r0a][1][ro];
                bf16x8 a1  = *(const bf16x8*)&fa1[ro];
                cf00a = MFMA(a00, p2A, cf00a); cf01a = MFMA(a00, p2B, cf01a);
                cf00b = MFMA(a01, p2A, cf00b); cf01b = MFMA(a01, p2B, cf01b);
                cf10  = MFMA(a1,  p2A, cf10);  cf11  = MFMA(a1,  p2B, cf11);
                int nf = base + 5; if (nf > 23) nf = 23;
                p2A = bpv[((16 + nf) * 16 + cw0) * 64 + lane];
                p2B = bpv[((16 + nf) * 16 + cw1) * 64 + lane];
            }
        }
        f32x4 cf00 = cf00a + cf00b, cf01 = cf01a + cf01b;
        // tile1 full = hi (quads 0,1) + lo (quads 2,3): combine across lane^32
        float cf10f[4], cf11f[4];
#pragma unroll
        for (int i = 0; i < 4; ++i) {
            cf10f[i] = cf10[i] + __shfl_xor(cf10[i], 32, 64);
            cf11f[i] = cf11[i] + __shfl_xor(cf11[i], 32, 64);
        }
        // writeback + fold bias and drive: Gl2[j][16w+l15] = {far+bias+drive, s0g/s1g}
#pragma unroll
        for (int i = 0; i < 4; ++i) {
            int j0 = 4 * quad + i;
            int tx0 = t0 + j0; float xv0 = xs[tx0 < TT ? tx0 : TT - 1];
            Gl2[j0][16 * w + l15] =
                make_float2(cf00[i] + bi0 + xv0 * win0, cf01[i] + bi1 + xv0 * win1);
            int j1 = 16 + 4 * quad + i;
            if (j1 < BLK) {
                int tx1 = t0 + j1; float xv1 = xs[tx1 < TT ? tx1 : TT - 1];
                Gl2[j1][16 * w + l15] =
                    make_float2(cf10f[i] + bi0 + xv1 * win0, cf11f[i] + bi1 + xv1 * win1);
            }
        }
        __syncthreads();

        // ---- sequential sub-blocks of 4 steps ----
        const int tend = (t0 + BLK < TT) ? (t0 + BLK) : TT;
#pragma unroll 1
        for (int t4 = t0; t4 < tend; t4 += 4) {
            // tap d=4, row-packed: rows 0-3,8-11 = steps hi; rows 4-7,12-15 = lo.
            f32x4 c40 = zf, c41 = zf;
            const int sl = (t4 - 4 + (l15 & 3)) & 7;
            const unsigned short* hw4 = hw4v + (size_t)sl * HWSLOT;
#pragma unroll
            for (int kt = 0; kt < 8; ++kt) {
                int ro = 32 * kt + 8 * quad;
                bf16x8 a = *(const bf16x8*)&hw4[ro];
                c40 = MFMA(a, b4[kt][0], c40);
                c41 = MFMA(a, b4[kt][1], c41);
            }
            // combine hi+lo across lane^16 (valid on all lanes)
            float c40f[4], c41f[4];
#pragma unroll
            for (int u2 = 0; u2 < 4; ++u2) {
                c40f[u2] = c40[u2] + __shfl_xor(c40[u2], 16, 64);
                c41f[u2] = c41[u2] + __shfl_xor(c41[u2], 16, 64);
            }
            // 4 sequential steps; tap d=1 per step, row-packed hi/lo (1 chain/nt)
#pragma unroll
            for (int u = 0; u < 4; ++u) {
                const int t = t4 + u;
                const int sp = (t - 1) & 7;
                const unsigned short* hw1 = hw1v + (size_t)sp * HWSLOT;
                f32x4 c10 = zf, c11 = zf;
#pragma unroll
                for (int kt = 0; kt < 8; ++kt) {
                    int ro = 32 * kt + 8 * quad;
                    bf16x8 a = *(const bf16x8*)&hw1[ro];
                    c10 = MFMA(a, b1[kt][0], c10);
                    c11 = MFMA(a, b1[kt][1], c11);
                }
                // update: C rows 4q (hi) and 4q+1 (lo) valid on EVERY quad ->
                // all 64 lanes compute identical h0,h1.
                const int jj = t - t0;
                const int wsl = t & 7;
                float2 gl = Gl2[jj][16 * w + l15];
                float f0 = (c10[0] + c10[1]) + c40f[u] + gl.x;
                float f1 = (c11[0] + c11[1]) + c41f[u] + gl.y;
                float h0 = 0.9f * hp0 + 0.1f * fast_tanh(f0);
                float h1 = 0.9f * hp1 + 0.1f * fast_tanh(f1);
                hp0 = h0; hp1 = h1;
                unsigned short hh0 = f2bf(h0), hh1 = f2bf(h1);
                unsigned short lo0 = f2bf(h0 - bf2f(hh0)), lo1 = f2bf(h1 - bf2f(hh1));
                // one packed write: quad selects {hi,lo} x {s0,s1}
                unsigned short v0 = varw ? lo0 : hh0;
                unsigned short v1 = varw ? lo1 : hh1;
                unsigned short wv = (quad & 1) ? v1 : v0;
                hwb[(size_t)wsl * HWSLOT + hw_off] = wv;
                if (quad < 2) hob[jj][s_w] = (quad & 1) ? h1 : h0;
                __syncthreads();
            }
        }

        // ---- flush hob -> out, coalesced float4 (drains at next block's barrier;
        //      earliest global re-read of these rows is 3 blocks later) ----
        {
            const int nf4 = (tend - t0) * (RR / 4);       // 1536, or 512 in last block
            const float4* src = (const float4*)&hob[0][0];
            float4* dst = (float4*)(outw + (size_t)t0 * RR);
#pragma unroll
            for (int it = 0; it < 3; ++it) {
                int idx = it * NTHR + tid;
                if (idx < nf4) dst[idx] = src[idx];
            }
        }
    }
}

extern "C" void kernel_launch(void* const* d_in, const int* in_sizes, int n_in,
                              void* d_out, int out_size, void* d_ws, size_t ws_size,
                              hipStream_t stream) {
    const float* x    = (const float*)d_in[0];   // (64, 2048, 1)
    const float* W_in = (const float*)d_in[1];   // (256, 1)
    const float* W_fb = (const float*)d_in[2];   // (5, 256, 256)
    const float* tapw = (const float*)d_in[3];   // (5,)
    const float* bias = (const float*)d_in[4];   // (256,)
    float* out = (float*)d_out;                  // (64, 2048, 256)
    unsigned short* bp = (unsigned short*)d_ws;  // 640 KB packed bf16 B-fragments

    pack_weights<<<160, 256, 0, stream>>>(W_fb, tapw, bp);
    reservoir_mfma<<<BB, NTHR, 0, stream>>>(x, W_in, bias, bp, out);
}